// Round 5
// baseline (515.081 us; speedup 1.0000x reference)
//
#include <hip/hip_runtime.h>
#include <hip/hip_bf16.h>

// GCN layer on MI355X, v5: split kernels, 16 waves/CU in both passes.
//   pass 1 (gcn_prep): 16 rows/block (2 rows/wave, 32 lanes/row), grid 512+32
//                      -> 2 blocks/CU, 4 waves/SIMD. rowsum(adj)+1 -> dinv;
//                      adjb = bf16(adj) in MFMA-fragment order [rt][ks][64][8];
//                      yT[f][j] = bf16(dinv_j * x[j][f]); tails: Wb = bf16(W)
//   pass 2 (gcn_main): 16-row tiles, grid 512 -> 2 blocks/CU. Pure bf16 GEMM
//                      h0 = adjb @ y, A via global_load_lds width=16 (linear
//                      lane-major -> conflict-free ds_read at lane*8 shorts).
//                      t = dinv_i*h0 + dinv_i^2*x; z = t@W^T + b;
//                      out = z / max(||z||_2, eps)
//
// ws: [0,2MB) yT | [2MB,+32KB) dinv | +32KB Wb | [4MB,+128MB) adjb packed

typedef __attribute__((ext_vector_type(8))) short short8;     // 8 x bf16
typedef __attribute__((ext_vector_type(4))) float f32x4;      // MFMA acc
typedef __attribute__((ext_vector_type(4))) unsigned short us4;

static __device__ __forceinline__ unsigned short f2bf(float f) {
    unsigned int u = __float_as_uint(f);
    u += 0x7FFFu + ((u >> 16) & 1u);
    return (unsigned short)(u >> 16);
}

static __device__ __forceinline__ void gload16(const void* g, const void* l) {
    __builtin_amdgcn_global_load_lds(
        (const __attribute__((address_space(1))) unsigned int*)g,
        (__attribute__((address_space(3))) unsigned int*)l, 16, 0, 0);
}

// ---------------------------------------------------------------- pass 1 ----
// 512 row-blocks (16 rows each: 8 waves x 2 rows, 32 lanes/row) + 32 W-blocks
__global__ __launch_bounds__(512) void gcn_prep(
    const float* __restrict__ adj, const float* __restrict__ x,
    const float* __restrict__ W,
    unsigned short* __restrict__ yT, float* __restrict__ dinv,
    unsigned short* __restrict__ Wb, unsigned short* __restrict__ adjb)
{
    const int tid = threadIdx.x;
    const int blk = blockIdx.x;
    if (blk >= 512) {                       // tail: convert W -> bf16
        int idx = (blk - 512) * 512 + tid;  // 32*512 = 16384 = 128*128
        Wb[idx] = f2bf(W[idx]);
        return;
    }
    const int wave = tid >> 6;
    const int lane = tid & 63;
    const int half = lane >> 5;             // 2 rows per wave
    const int l32  = lane & 31;             // 32 lanes per row
    const long j0  = (long)blk * 16;
    const long row = j0 + wave * 2 + half;
    const int rt = (int)(row >> 4);         // packed-tile row group
    const int ln = (int)(row & 15);
    const int q  = (l32 & 7) >> 1;          // k-quad within 32-k step
    const int jj = (l32 & 1) * 4;           // short offset within 8-group

    __shared__ float s_di[16];

    // lane covers float4 index it*32 + l32, it = 0..63 (64 x 32 x 4 = 8192)
    const float4* rowp = (const float4*)(adj + row * 8192L);
    float s = 0.f;
#pragma unroll 1
    for (int bt = 0; bt < 8; ++bt) {        // 8 batches of 8 in-flight loads
        float4 st[8];
#pragma unroll
        for (int i = 0; i < 8; ++i)
            st[i] = rowp[(bt * 8 + i) * 32 + l32];
#pragma unroll
        for (int i = 0; i < 8; ++i) {
            float4 v = st[i];
            s += (v.x + v.y) + (v.z + v.w);
            int it = bt * 8 + i;
            int ks = it * 4 + (l32 >> 3);   // k-step = (it*128 + l32*4) >> 5
            us4 w4;
            w4.x = f2bf(v.x); w4.y = f2bf(v.y);
            w4.z = f2bf(v.z); w4.w = f2bf(v.w);
            // packed: [rt][ks][lane'=q*16+ln][8 shorts]
            *(us4*)&adjb[(((long)rt * 256 + ks) * 64 + q * 16 + ln) * 8 + jj] = w4;
        }
    }
    // reduce over the 32 lanes of this row (stays within 32-lane half)
    s += __shfl_xor(s, 1, 64);
    s += __shfl_xor(s, 2, 64);
    s += __shfl_xor(s, 4, 64);
    s += __shfl_xor(s, 8, 64);
    s += __shfl_xor(s, 16, 64);
    if (l32 == 0) s_di[wave * 2 + half] = rsqrtf(s + 1.0f);  // +1: self loop
    __syncthreads();
    if (tid < 16) dinv[j0 + tid] = s_di[tid];

    // yT write: 16 consecutive threads = one 32B segment yT[f][j0..j0+15]
    const int jy = tid & 15;
    const int f0 = tid >> 4;                // 0..31
    const float di = s_di[jy];
#pragma unroll
    for (int p = 0; p < 4; ++p) {
        int f = p * 32 + f0;
        yT[(long)f * 8192 + j0 + jy] = f2bf(di * x[(int)(j0 + jy) * 128 + f]);
    }
}

// ---------------------------------------------------------------- pass 2 ----
#define CK 16                 // k-steps per chunk (16 x 32 = 512 k)
#define NCHUNK 16             // 8192 / 512

// 512 blocks x 512 thr (8 waves), 16 rows/block -> 2 blocks/CU.
// Wave w: cols w*16..w*16+15 (unique), all 16 rows.
__global__ __launch_bounds__(512) void gcn_main(
    const unsigned short* __restrict__ adjb, const float* __restrict__ x,
    const float* __restrict__ bias,
    const unsigned short* __restrict__ yT, const float* __restrict__ dinv,
    const unsigned short* __restrict__ Wb, float* __restrict__ out)
{
    __shared__ unsigned short AbS[2][16 * 512];   // 2 x 16KB (16 slots x 1KB)

    const int tid  = threadIdx.x;
    const int wave = tid >> 6;        // 0..7
    const int lane = tid & 63;
    const int q    = lane >> 4;
    const int ln   = lane & 15;
    const int blk  = blockIdx.x;
    const long rowBase = (long)blk * 16;

    f32x4 acc = {};                   // 16 rows x 16 cols per wave

    // stage one 16KB chunk (16 slots of 1KB); slot s = ks within chunk
    auto stage = [&](int c, int buf) {
#pragma unroll
        for (int i = 0; i < 2; ++i) {
            int s = wave * 2 + i;
            const char* src = (const char*)adjb +
                (((long)blk * 256 + c * CK + s) * 64 + lane) * 16;
            gload16(src, &AbS[buf][s * 512]);
        }
    };

    stage(0, 0);
    __syncthreads();

    const unsigned short* bcol = &yT[(wave * 16 + ln) * 8192L + q * 8];

#pragma unroll 1
    for (int c = 0; c < NCHUNK; ++c) {
        const int cur = c & 1;
        if (c + 1 < NCHUNK) stage(c + 1, cur ^ 1);   // fire-and-forget
#pragma unroll
        for (int ks = 0; ks < CK; ++ks) {
            short8 a = *(const short8*)&AbS[cur][ks * 512 + lane * 8];
            short8 b = *(const short8*)&bcol[c * 512 + ks * 32];
            acc = __builtin_amdgcn_mfma_f32_16x16x32_bf16(a, b, acc, 0, 0, 0);
        }
        __syncthreads();       // staged loads landed; buffers safe to flip
    }

    // ---- fused epilogue (scratch overlays AbS[0]; last compute read AbS[1])
    unsigned short* t_lds = &AbS[0][0];             // [16][136] bf16 (pad 8)
    float* s_dinv = (float*)(t_lds + 16 * 136);
    float* s_part = s_dinv + 16;                    // [16][8] per-wave |z|^2
    float* s_inv  = s_part + 128;                   // [16]

    if (tid < 16) s_dinv[tid] = dinv[rowBase + tid];
    __syncthreads();

    // t = dinv_i * (adj@y)_i + dinv_i^2 * x_i  -> LDS (bf16)
#pragma unroll
    for (int r = 0; r < 4; ++r) {
        int m = q * 4 + r;
        int n = wave * 16 + ln;
        float di = s_dinv[m];
        float tv = di * acc[r] + di * di * x[(int)(rowBase + m) * 128 + n];
        t_lds[m * 136 + n] = f2bf(tv);
    }
    __syncthreads();

    // z = t @ W^T via MFMA
    f32x4 z = {};
#pragma unroll
    for (int s = 0; s < 4; ++s) {
        const int k0 = s * 32 + q * 8;
        short8 a = *(const short8*)&t_lds[ln * 136 + k0];
        short8 b = *(const short8*)&Wb[(wave * 16 + ln) * 128 + k0];
        z = __builtin_amdgcn_mfma_f32_16x16x32_bf16(a, b, z, 0, 0, 0);
    }

    // + bias, |z|^2 partials over this wave's 16 cols
    float bv = bias[wave * 16 + ln];
    float zv[4], rp[4];
#pragma unroll
    for (int r = 0; r < 4; ++r) {
        float v = z[r] + bv;
        zv[r] = v;
        rp[r] = v * v;
    }
#pragma unroll
    for (int r = 0; r < 4; ++r) {
        rp[r] += __shfl_xor(rp[r], 1, 64);
        rp[r] += __shfl_xor(rp[r], 2, 64);
        rp[r] += __shfl_xor(rp[r], 4, 64);
        rp[r] += __shfl_xor(rp[r], 8, 64);
    }
    if (ln == 0) {
#pragma unroll
        for (int r = 0; r < 4; ++r)
            s_part[(q * 4 + r) * 8 + wave] = rp[r];
    }
    __syncthreads();
    if (tid < 16) {
        float s = 0.f;
#pragma unroll
        for (int w = 0; w < 8; ++w) s += s_part[tid * 8 + w];
        s_inv[tid] = 1.0f / fmaxf(sqrtf(s), 1e-12f);   // F.normalize eps
    }
    __syncthreads();

#pragma unroll
    for (int r = 0; r < 4; ++r) {
        int m = q * 4 + r;
        out[(int)(rowBase + m) * 128 + wave * 16 + ln] = zv[r] * s_inv[m];
    }
}

// ---------------------------------------------------------------- launch ----
extern "C" void kernel_launch(void* const* d_in, const int* in_sizes, int n_in,
                              void* d_out, int out_size, void* d_ws, size_t ws_size,
                              hipStream_t stream) {
    const float* x   = (const float*)d_in[0];   // [8192,128]
    const float* adj = (const float*)d_in[1];   // [8192,8192]
    const float* W   = (const float*)d_in[2];   // [128,128]
    const float* b   = (const float*)d_in[3];   // [128]
    float* out = (float*)d_out;

    unsigned short* yT   = (unsigned short*)d_ws;                          // 2MB
    float*          dv   = (float*)((char*)d_ws + (2u << 20));             // 32KB
    unsigned short* Wb   = (unsigned short*)((char*)d_ws + (2u << 20) + 32768);
    unsigned short* adjb = (unsigned short*)((char*)d_ws + (4u << 20));    // 128MB

    gcn_prep<<<512 + 32, 512, 0, stream>>>(adj, x, W, yT, dv, Wb, adjb);
    gcn_main<<<512, 512, 0, stream>>>(adjb, x, b, yT, dv, Wb, out);
}

// Round 6
// 468.423 us; speedup vs baseline: 1.0996x; 1.0996x over previous
//
#include <hip/hip_runtime.h>
#include <hip/hip_bf16.h>

// GCN layer on MI355X, v6: r3 architecture; prep occupancy fixed via k-split.
//   pass 1 (gcn_prep): 16 rows/block, 8 waves: wave = (row-quad wq, k-half h).
//                      Each wave: 4 consecutive rows x 16 lanes x 4096 k.
//                      -> 512 blocks (2/CU, 4 waves/SIMD), adjb 64B-line writes
//                      preserved (4 consecutive rows per wave). rowsum halves
//                      combined in LDS -> dinv; yT[f][j] = bf16(dinv_j*x[j][f]);
//                      tail blocks: Wb = bf16(W)
//   pass 2 (gcn_main): UNCHANGED from r3 (best measured): 32-row tiles,
//                      grid 256, pure bf16 GEMM h0 = adjb @ y via
//                      global_load_lds width=16, fused epilogue
//                      t = dinv_i*h0 + dinv_i^2*x; z = t@W^T + b;
//                      out = z / max(||z||_2, eps)
//
// ws: [0,2MB) yT | [2MB,+32KB) dinv | +32KB Wb | [4MB,+128MB) adjb packed

typedef __attribute__((ext_vector_type(8))) short short8;     // 8 x bf16
typedef __attribute__((ext_vector_type(4))) float f32x4;      // MFMA acc
typedef __attribute__((ext_vector_type(4))) unsigned short us4;

static __device__ __forceinline__ unsigned short f2bf(float f) {
    unsigned int u = __float_as_uint(f);
    u += 0x7FFFu + ((u >> 16) & 1u);
    return (unsigned short)(u >> 16);
}

static __device__ __forceinline__ void gload16(const void* g, const void* l) {
    __builtin_amdgcn_global_load_lds(
        (const __attribute__((address_space(1))) unsigned int*)g,
        (__attribute__((address_space(3))) unsigned int*)l, 16, 0, 0);
}

// ---------------------------------------------------------------- pass 1 ----
// 512 row-blocks (16 rows; waves: 4 row-quads x 2 k-halves) + 32 W-blocks
__global__ __launch_bounds__(512) void gcn_prep(
    const float* __restrict__ adj, const float* __restrict__ x,
    const float* __restrict__ W,
    unsigned short* __restrict__ yT, float* __restrict__ dinv,
    unsigned short* __restrict__ Wb, unsigned short* __restrict__ adjb)
{
    const int tid = threadIdx.x;
    const int blk = blockIdx.x;
    if (blk >= 512) {                       // tail: convert W -> bf16
        int idx = (blk - 512) * 512 + tid;  // 32*512 = 16384 = 128*128
        Wb[idx] = f2bf(W[idx]);
        return;
    }
    const int wave   = tid >> 6;
    const int lane   = tid & 63;
    const int wq     = wave & 3;            // row-quad within block (0..3)
    const int h      = wave >> 2;           // k-half (0..1)
    const int rowsel = lane >> 4;           // 4 rows per wave
    const int l16    = lane & 15;           // 16 lanes per row
    const long j0  = (long)blk * 16;
    const long row = j0 + wq * 4 + rowsel;  // 4 consecutive rows/wave ->
    const int rt = (int)(row >> 4);         //   full 64B adjb line writes
    const int ln = (int)(row & 15);
    const int q  = (l16 >> 1) & 3;
    const int jj = (l16 & 1) * 4;

    __shared__ float s_half[16][2];
    __shared__ float s_di[16];

    // this wave covers k in [h*4096, h*4096+4096): 64 iters x 16 lanes x 4
    const float4* rowp = (const float4*)(adj + row * 8192L) + (long)h * 1024;
    float s = 0.f;
#pragma unroll 1
    for (int bt = 0; bt < 8; ++bt) {        // 8 batches of 8 in-flight loads
        float4 st[8];
#pragma unroll
        for (int i = 0; i < 8; ++i)
            st[i] = rowp[(bt * 8 + i) * 16 + l16];
#pragma unroll
        for (int i = 0; i < 8; ++i) {
            float4 v = st[i];
            s += (v.x + v.y) + (v.z + v.w);
            int it = bt * 8 + i;
            int ks = h * 128 + it * 2 + (l16 >> 3);   // k-step (32k each)
            us4 w4;
            w4.x = f2bf(v.x); w4.y = f2bf(v.y);
            w4.z = f2bf(v.z); w4.w = f2bf(v.w);
            // packed: [rt][ks][lane'=q*16+ln][8 shorts]; per (ks,q) the wave's
            // 4 rows x 2 jj form one full 64B line
            *(us4*)&adjb[(((long)rt * 256 + ks) * 64 + q * 16 + ln) * 8 + jj] = w4;
        }
    }
    // reduce partial rowsum over the 16 lanes of this row-half
    s += __shfl_xor(s, 1, 64);
    s += __shfl_xor(s, 2, 64);
    s += __shfl_xor(s, 4, 64);
    s += __shfl_xor(s, 8, 64);
    if (l16 == 0) s_half[wq * 4 + rowsel][h] = s;
    __syncthreads();
    if (tid < 16) {
        float di = rsqrtf(s_half[tid][0] + s_half[tid][1] + 1.0f);  // +1 self
        dinv[j0 + tid] = di;
        s_di[tid] = di;
    }
    __syncthreads();

    // yT write: 16 consecutive threads = one 32B segment yT[f][j0..j0+15]
    const int jy = tid & 15;
    const int f0 = tid >> 4;                // 0..31
    const float di = s_di[jy];
#pragma unroll
    for (int p = 0; p < 4; ++p) {
        int f = p * 32 + f0;
        yT[(long)f * 8192 + j0 + jy] = f2bf(di * x[(j0 + jy) * 128 + f]);
    }
}

// ---------------------------------------------------------------- pass 2 ----
#define CK 16                 // k-steps per chunk (16 x 32 = 512 k)
#define NCHUNK 16             // 8192 / 512

// 256 blocks x 512 thr (8 waves). Block: 32 rows (2 row-tiles) x 128 cols.
// Wave w: cols w*16..w*16+15 (unique -> B read once/block), both row-tiles.
__global__ __launch_bounds__(512) void gcn_main(
    const unsigned short* __restrict__ adjb, const float* __restrict__ x,
    const float* __restrict__ bias,
    const unsigned short* __restrict__ yT, const float* __restrict__ dinv,
    const unsigned short* __restrict__ Wb, float* __restrict__ out)
{
    __shared__ unsigned short AbS[2][32 * 512];   // 2 x 32KB (32 slots x 1KB)

    const int tid  = threadIdx.x;
    const int wave = tid >> 6;        // 0..7
    const int lane = tid & 63;
    const int q    = lane >> 4;
    const int ln   = lane & 15;
    const int blk  = blockIdx.x;
    const long rowBase = (long)blk * 32;

    f32x4 acc[2] = {};                // [rt] : 2x16 rows x 16 cols

    // stage one 32KB chunk (32 slots of 1KB); slot s = (rt*16 + ks)
    auto stage = [&](int c, int buf) {
#pragma unroll
        for (int i = 0; i < 4; ++i) {
            int s = i * 8 + wave;
            const char* src = (const char*)adjb +
                ((((long)(blk * 2 + (s >> 4))) * 256 + c * CK + (s & 15)) * 64 + lane) * 16;
            gload16(src, &AbS[buf][s * 512]);
        }
    };

    stage(0, 0);
    __syncthreads();

    const unsigned short* bcol = &yT[(wave * 16 + ln) * 8192L + q * 8];

#pragma unroll 1
    for (int c = 0; c < NCHUNK; ++c) {
        const int cur = c & 1;
        if (c + 1 < NCHUNK) stage(c + 1, cur ^ 1);   // fire-and-forget
#pragma unroll
        for (int ks = 0; ks < CK; ++ks) {
            short8 a0 = *(const short8*)&AbS[cur][ks * 512 + lane * 8];
            short8 a1 = *(const short8*)&AbS[cur][(16 + ks) * 512 + lane * 8];
            short8 b  = *(const short8*)&bcol[c * 512 + ks * 32];
            acc[0] = __builtin_amdgcn_mfma_f32_16x16x32_bf16(a0, b, acc[0], 0, 0, 0);
            acc[1] = __builtin_amdgcn_mfma_f32_16x16x32_bf16(a1, b, acc[1], 0, 0, 0);
        }
        __syncthreads();       // staged loads landed; buffers safe to flip
    }

    // ---- fused epilogue (scratch overlays AbS[0]; last compute read AbS[1])
    unsigned short* t_lds = &AbS[0][0];             // [32][136] bf16 (pad 8)
    float* s_dinv = (float*)(t_lds + 32 * 136);
    float* s_part = s_dinv + 32;                    // [32][8] per-wave |z|^2
    float* s_inv  = s_part + 256;                   // [32]

    if (tid < 32) s_dinv[tid] = dinv[rowBase + tid];
    __syncthreads();

    // t = dinv_i * (adj@y)_i + dinv_i^2 * x_i  -> LDS (bf16)
#pragma unroll
    for (int rt = 0; rt < 2; ++rt)
#pragma unroll
        for (int r = 0; r < 4; ++r) {
            int m = rt * 16 + q * 4 + r;
            int n = wave * 16 + ln;
            float di = s_dinv[m];
            float tv = di * acc[rt][r] + di * di * x[(rowBase + m) * 128 + n];
            t_lds[m * 136 + n] = f2bf(tv);
        }
    __syncthreads();

    // z = t @ W^T via MFMA
    f32x4 z[2] = {};
#pragma unroll
    for (int s = 0; s < 4; ++s) {
        const int k0 = s * 32 + q * 8;
        short8 a0 = *(const short8*)&t_lds[ln * 136 + k0];
        short8 a1 = *(const short8*)&t_lds[(16 + ln) * 136 + k0];
        short8 b  = *(const short8*)&Wb[(wave * 16 + ln) * 128 + k0];
        z[0] = __builtin_amdgcn_mfma_f32_16x16x32_bf16(a0, b, z[0], 0, 0, 0);
        z[1] = __builtin_amdgcn_mfma_f32_16x16x32_bf16(a1, b, z[1], 0, 0, 0);
    }

    // + bias, |z|^2 partials over this wave's 16 cols
    float bv = bias[wave * 16 + ln];
    float zv[2][4], rp[2][4];
#pragma unroll
    for (int rt = 0; rt < 2; ++rt)
#pragma unroll
        for (int r = 0; r < 4; ++r) {
            float v = z[rt][r] + bv;
            zv[rt][r] = v;
            rp[rt][r] = v * v;
        }
#pragma unroll
    for (int rt = 0; rt < 2; ++rt)
#pragma unroll
        for (int r = 0; r < 4; ++r) {
            rp[rt][r] += __shfl_xor(rp[rt][r], 1, 64);
            rp[rt][r] += __shfl_xor(rp[rt][r], 2, 64);
            rp[rt][r] += __shfl_xor(rp[rt][r], 4, 64);
            rp[rt][r] += __shfl_xor(rp[rt][r], 8, 64);
        }
    if (ln == 0) {
#pragma unroll
        for (int rt = 0; rt < 2; ++rt)
#pragma unroll
            for (int r = 0; r < 4; ++r)
                s_part[(rt * 16 + q * 4 + r) * 8 + wave] = rp[rt][r];
    }
    __syncthreads();
    if (tid < 32) {
        float s = 0.f;
#pragma unroll
        for (int w = 0; w < 8; ++w) s += s_part[tid * 8 + w];
        s_inv[tid] = 1.0f / fmaxf(sqrtf(s), 1e-12f);   // F.normalize eps
    }
    __syncthreads();

#pragma unroll
    for (int rt = 0; rt < 2; ++rt)
#pragma unroll
        for (int r = 0; r < 4; ++r) {
            int m = rt * 16 + q * 4 + r;
            out[(rowBase + m) * 128 + wave * 16 + ln] = zv[rt][r] * s_inv[m];
        }
}

// ---------------------------------------------------------------- launch ----
extern "C" void kernel_launch(void* const* d_in, const int* in_sizes, int n_in,
                              void* d_out, int out_size, void* d_ws, size_t ws_size,
                              hipStream_t stream) {
    const float* x   = (const float*)d_in[0];   // [8192,128]
    const float* adj = (const float*)d_in[1];   // [8192,8192]
    const float* W   = (const float*)d_in[2];   // [128,128]
    const float* b   = (const float*)d_in[3];   // [128]
    float* out = (float*)d_out;

    unsigned short* yT   = (unsigned short*)d_ws;                          // 2MB
    float*          dv   = (float*)((char*)d_ws + (2u << 20));             // 32KB
    unsigned short* Wb   = (unsigned short*)((char*)d_ws + (2u << 20) + 32768);
    unsigned short* adjb = (unsigned short*)((char*)d_ws + (4u << 20));    // 128MB

    gcn_prep<<<512 + 32, 512, 0, stream>>>(adj, x, W, yT, dv, Wb, adjb);
    gcn_main<<<256, 512, 0, stream>>>(adjb, x, b, yT, dv, Wb, out);
}